// Round 16
// baseline (35.242 us; speedup 1.0000x reference)
//
#include <hip/hip_runtime.h>
#include <hip/hip_bf16.h>

// CRF loss: B=32, S=128, V=8, T=66.  256 chains; 2 waves per chain:
// wave0 = forward exp-domain recurrence (steps 1..63)  -> F = exp(alpha_63 - cF)
// wave1 = backward exp-domain recurrence (steps 127..64)-> G = exp(beta_63 - cG)
// Z = 2^(esumF+esumG) * sum_i F_i G_i.  Exact 2^-e rescaling; no div/exp/log
// on the critical path.  Lane broadcast of the state vector is done via LDS
// (1 ds_write + 16 same-address ds_read_b128, double-buffered, no barrier)
// instead of 64 v_readlane ops.
constexpr int TT = 66;
constexpr int SS = 128;
constexpr int NV = 8;

__device__ __forceinline__ float rl(float v, int lane) {
    return __int_as_float(__builtin_amdgcn_readlane(__float_as_int(v), lane));
}

__global__ __launch_bounds__(128) void crf_chain_kernel(
    const float* __restrict__ score,        // [32,128,128,66]
    const float* __restrict__ trans,        // [66,66]
    const float* __restrict__ startt,       // [66]
    const float* __restrict__ endt,         // [66]
    const int*   __restrict__ v_label,      // [32,8]
    const int*   __restrict__ role_label,   // [32,8,128]
    float*       __restrict__ ws_nll)       // [256] per-chain nll
{
    __shared__ __align__(16) float xl[SS * TT];     // X = exp(emissions), 33792 B
    __shared__ __align__(16) float fbc[2][2][64];   // [wave][buf][lane] broadcast
    __shared__ float gbuf[TT + 2];                  // G exchange + esumG
    const int tid  = threadIdx.x;
    const int lane = tid & 63;
    const int wid  = tid >> 6;
    const int bv   = blockIdx.x;
    const int b    = bv >> 3;
    const int v    = bv & 7;

    // ---- stage exp(emissions), split by wave half (1056 float4 each) ----
    // wave0: float4 [0,1056)  = rows 0..63 ; wave1: float4 [1056,2112) = rows 64..127
    const int prow = v_label[b * NV + v];
    const float* src = score + ((size_t)(b * SS + prow) * (SS * TT));
    const float4* src4 = reinterpret_cast<const float4*>(src);
    float4* dst4 = reinterpret_cast<float4*>(xl);
    const int base4 = wid * 1056;
    #pragma unroll
    for (int k = 0; k < 16; ++k) {                // 16*64 = 1024 float4
        const int idx = base4 + k * 64 + lane;
        float4 tv = src4[idx];
        tv.x = __expf(tv.x); tv.y = __expf(tv.y);
        tv.z = __expf(tv.z); tv.w = __expf(tv.w);
        dst4[idx] = tv;
    }
    if (lane < 32) {                              // tail 32 float4 per wave
        const int idx = base4 + 1024 + lane;
        float4 tv = src4[idx];
        tv.x = __expf(tv.x); tv.y = __expf(tv.y);
        tv.z = __expf(tv.z); tv.w = __expf(tv.w);
        dst4[idx] = tv;
    }
    // no barrier: each wave reads only the half it wrote (same-wave LDS dep)

    // ---- gold score (wave 0 only; global reads) ----
    const int* tags = role_label + bv * SS;
    float gold = 0.f;
    if (wid == 0) {
        const int s0 = lane;                      // 0..63
        const int tg0 = tags[s0];
        gold += src[s0 * TT + tg0];
        gold += trans[tg0 * TT + tags[s0 + 1]];
        const int s1 = lane + 64;                 // 64..127
        const int tg1 = tags[s1];
        gold += src[s1 * TT + tg1];
        if (lane < 63) gold += trans[tg1 * TT + tags[s1 + 1]];
        #pragma unroll
        for (int off = 32; off; off >>= 1) gold += __shfl_xor(gold, off);
        gold += startt[tags[0]] + endt[tags[SS - 1]];
    }

    // ---- per-wave weights ----
    // wave0 (forward): W[i]  = exp(trans[i][lane])    (column `lane`)
    //                  W2[i] = exp(trans[i][64|65])   (lanes 0/1 -> cols 64/65)
    // wave1 (backward): W[j] = exp(trans[lane][j])    (row `lane`)
    //                  W2[j] = exp(trans[64|65][j])   (lanes 0/1 -> rows 64/65)
    const int xsel = (lane == 1) ? 65 : 64;
    float W[TT], W2[TT];
    if (wid == 0) {
        #pragma unroll
        for (int i = 0; i < TT; ++i) {
            W[i]  = __expf(trans[i * TT + lane]);
            W2[i] = __expf(trans[i * TT + xsel]);
        }
    } else {
        #pragma unroll
        for (int j = 0; j < TT; ++j) {
            W[j]  = __expf(trans[lane * TT + j]);
            W2[j] = __expf(trans[xsel * TT + j]);
        }
    }

    float* fb_w = &fbc[wid][0][0];                // this wave's broadcast region

    int esum = 0;
    float F = 0.f, F64 = 0.f, F65 = 0.f;          // wave0 result
    if (wid == 0) {
        // ---- forward: F(0) = exp(start) * X_0; steps t = 1..63 ----
        F   = __expf(startt[lane]) * xl[lane];
        F64 = __expf(startt[64])   * xl[64];
        F65 = __expf(startt[65])   * xl[65];
        fb_w[lane] = F;                           // broadcast buffer 0
        int rb = 0;
        float xc   = xl[TT + lane];
        float xc64 = xl[TT + 64];
        float xc65 = xl[TT + 65];
        #pragma unroll 1
        for (int t = 1; t <= 63; ++t) {
            const int tn = (t < 63) ? t + 1 : t;
            const float xn   = xl[tn * TT + lane];
            const float xn64 = xl[tn * TT + 64];
            const float xn65 = xl[tn * TT + 65];

            const float4* fb = reinterpret_cast<const float4*>(fb_w + rb * 64);
            float acc0 = F64 * W[64],  acc1 = F65 * W[65];
            float acc2 = 0.f,          acc3 = 0.f;
            float ex0  = F64 * W2[64], ex1  = F65 * W2[65];
            float ex2  = 0.f,          ex3  = 0.f;
            #pragma unroll
            for (int k = 0; k < 16; ++k) {
                const float4 q = fb[k];           // same-address broadcast read
                const int i = k * 4;
                acc0 = fmaf(q.x, W[i + 0], acc0);  ex0 = fmaf(q.x, W2[i + 0], ex0);
                acc1 = fmaf(q.y, W[i + 1], acc1);  ex1 = fmaf(q.y, W2[i + 1], ex1);
                acc2 = fmaf(q.z, W[i + 2], acc2);  ex2 = fmaf(q.z, W2[i + 2], ex2);
                acc3 = fmaf(q.w, W[i + 3], acc3);  ex3 = fmaf(q.w, W2[i + 3], ex3);
            }
            const float S  = (acc0 + acc1) + (acc2 + acc3);
            const float Sx = (ex0 + ex1) + (ex2 + ex3);
            const float S64 = rl(Sx, 0);
            const float S65 = rl(Sx, 1);

            const int sbits = __builtin_amdgcn_readfirstlane(__float_as_int(S));
            const int e = ((sbits >> 23) & 0xff) - 127;
            esum += e;
            const float r = __int_as_float((127 - e) << 23);   // 2^-e exact

            F   = (S   * r) * xc;
            F64 = (S64 * r) * xc64;
            F65 = (S65 * r) * xc65;
            fb_w[(rb ^ 1) * 64 + lane] = F;       // write next broadcast
            rb ^= 1;
            xc = xn; xc64 = xn64; xc65 = xn65;
        }
    } else {
        // ---- backward: G(127) = exp(end); steps t = 127..64 ----
        float G   = __expf(endt[lane]);
        float G64 = __expf(endt[64]);
        float G65 = __expf(endt[65]);
        float xc   = xl[127 * TT + lane];
        float xc64 = xl[127 * TT + 64];
        float xc65 = xl[127 * TT + 65];
        fb_w[lane] = G * xc;                      // Y(127) broadcast buffer 0
        float Y64 = G64 * xc64;
        float Y65 = G65 * xc65;
        int rb = 0;
        #pragma unroll 1
        for (int t = 127; t >= 64; --t) {
            const int tn = (t > 64) ? t - 1 : t;
            const float xn   = xl[tn * TT + lane];
            const float xn64 = xl[tn * TT + 64];
            const float xn65 = xl[tn * TT + 65];

            const float4* fb = reinterpret_cast<const float4*>(fb_w + rb * 64);
            float acc0 = Y64 * W[64],  acc1 = Y65 * W[65];
            float acc2 = 0.f,          acc3 = 0.f;
            float ex0  = Y64 * W2[64], ex1  = Y65 * W2[65];
            float ex2  = 0.f,          ex3  = 0.f;
            #pragma unroll
            for (int k = 0; k < 16; ++k) {
                const float4 q = fb[k];           // same-address broadcast read
                const int i = k * 4;
                acc0 = fmaf(q.x, W[i + 0], acc0);  ex0 = fmaf(q.x, W2[i + 0], ex0);
                acc1 = fmaf(q.y, W[i + 1], acc1);  ex1 = fmaf(q.y, W2[i + 1], ex1);
                acc2 = fmaf(q.z, W[i + 2], acc2);  ex2 = fmaf(q.z, W2[i + 2], ex2);
                acc3 = fmaf(q.w, W[i + 3], acc3);  ex3 = fmaf(q.w, W2[i + 3], ex3);
            }
            const float S  = (acc0 + acc1) + (acc2 + acc3);
            const float Sx = (ex0 + ex1) + (ex2 + ex3);
            const float S64 = rl(Sx, 0);
            const float S65 = rl(Sx, 1);

            const int sbits = __builtin_amdgcn_readfirstlane(__float_as_int(S));
            const int e = ((sbits >> 23) & 0xff) - 127;
            esum += e;
            const float r = __int_as_float((127 - e) << 23);

            const float G_  = S   * r;            // state after step t
            const float G64_= S64 * r;
            const float G65_= S65 * r;
            // next broadcast: Y(t-1) = G * X_{t-1}  (harmless dummy at t=64)
            fb_w[(rb ^ 1) * 64 + lane] = G_ * xn;
            Y64 = G64_ * xn64;
            Y65 = G65_ * xn65;
            rb ^= 1;
            G = G_; G64 = G64_; G65 = G65_;
            xc = xn; xc64 = xn64; xc65 = xn65;
        }
        gbuf[lane] = G;
        if (lane == 0) {
            gbuf[64] = G64;
            gbuf[65] = G65;
            gbuf[66] = __int_as_float(esum);
        }
    }

    __syncthreads();

    if (wid == 0) {
        // ---- stitch: Z = 2^(esumF+esumG) * sum_i F_i * G_i ----
        float prod = F * gbuf[lane];
        #pragma unroll
        for (int off = 32; off; off >>= 1) prod += __shfl_xor(prod, off);
        const float tot = prod + F64 * gbuf[64] + F65 * gbuf[65];
        const int esumG = __float_as_int(gbuf[66]);
        const float log_z = (float)(esum + esumG) * 0.69314718056f + __logf(tot);
        if (lane == 0) ws_nll[bv] = log_z - gold;
    }
}

__global__ __launch_bounds__(64) void crf_reduce_kernel(
    const float* __restrict__ ws_nll, float* __restrict__ out)
{
    const int lane = threadIdx.x;
    float s = ws_nll[lane] + ws_nll[lane + 64] + ws_nll[lane + 128] + ws_nll[lane + 192];
    #pragma unroll
    for (int off = 32; off; off >>= 1) s += __shfl_xor(s, off);
    if (lane == 0) out[0] = s * (1.0f / 256.0f);
}

extern "C" void kernel_launch(void* const* d_in, const int* in_sizes, int n_in,
                              void* d_out, int out_size, void* d_ws, size_t ws_size,
                              hipStream_t stream) {
    const float* score  = (const float*)d_in[0];
    const float* trans  = (const float*)d_in[1];
    const float* startt = (const float*)d_in[2];
    const float* endt   = (const float*)d_in[3];
    const int*   v_label    = (const int*)d_in[4];
    const int*   role_label = (const int*)d_in[5];
    float* out = (float*)d_out;
    float* ws  = (float*)d_ws;

    crf_chain_kernel<<<256, 128, 0, stream>>>(score, trans, startt, endt,
                                              v_label, role_label, ws);
    crf_reduce_kernel<<<1, 64, 0, stream>>>(ws, out);
}

// Round 17
// 30.065 us; speedup vs baseline: 1.1722x; 1.1722x over previous
//
#include <hip/hip_runtime.h>
#include <hip/hip_bf16.h>

// CRF loss: B=32, S=128, V=8, T=66.  256 chains; 2 waves per chain:
// wave0 = forward exp-domain recurrence (steps 1..63)  -> F = exp(alpha_63 - cF)
// wave1 = backward exp-domain recurrence (steps 127..64)-> G = exp(beta_63 - cG)
// Z = 2^(esumF+esumG) * sum_i F_i G_i.  Exact 2^-e rescaling every 2nd step.
// Cols/rows 64,65 handled by DPP wave-reduction of lane-local partials
// (12 VALU ops) instead of a redundant 64-FMA second stream.
constexpr int TT = 66;
constexpr int SS = 128;
constexpr int NV = 8;

__device__ __forceinline__ float rl(float v, int lane) {
    return __int_as_float(__builtin_amdgcn_readlane(__float_as_int(v), lane));
}
template <int CTRL>
__device__ __forceinline__ float dpp_add(float x) {
    // x + dpp_mov(x, CTRL); bound_ctrl=true: out-of-range source lanes read 0
    int y = __builtin_amdgcn_update_dpp(0, __float_as_int(x), CTRL, 0xf, 0xf, true);
    return x + __int_as_float(y);
}
__device__ __forceinline__ float wave_reduce_sum(float x) {
    x = dpp_add<0x111>(x); // row_shr:1
    x = dpp_add<0x112>(x); // row_shr:2
    x = dpp_add<0x114>(x); // row_shr:4
    x = dpp_add<0x118>(x); // row_shr:8
    x = dpp_add<0x142>(x); // row_bcast:15
    x = dpp_add<0x143>(x); // row_bcast:31
    return x;              // lane 63 holds the 64-lane total
}

__global__ __launch_bounds__(128) void crf_chain_kernel(
    const float* __restrict__ score,        // [32,128,128,66]
    const float* __restrict__ trans,        // [66,66]
    const float* __restrict__ startt,       // [66]
    const float* __restrict__ endt,         // [66]
    const int*   __restrict__ v_label,      // [32,8]
    const int*   __restrict__ role_label,   // [32,8,128]
    float*       __restrict__ ws_nll)       // [256] per-chain nll
{
    __shared__ __align__(16) float xl[SS * TT];   // X = exp(emissions), 33792 B
    __shared__ float gbuf[TT + 2];                // G exchange + esumG
    const int tid  = threadIdx.x;
    const int lane = tid & 63;
    const int wid  = tid >> 6;
    const int bv   = blockIdx.x;
    const int b    = bv >> 3;
    const int v    = bv & 7;

    // ---- stage exp(emissions), split by wave half (1056 float4 each) ----
    // wave0: float4 [0,1056)  = rows 0..63 ; wave1: float4 [1056,2112) = rows 64..127
    const int prow = v_label[b * NV + v];
    const float* src = score + ((size_t)(b * SS + prow) * (SS * TT));
    const float4* src4 = reinterpret_cast<const float4*>(src);
    float4* dst4 = reinterpret_cast<float4*>(xl);
    const int base4 = wid * 1056;
    #pragma unroll
    for (int k = 0; k < 16; ++k) {                // 16*64 = 1024 float4
        const int idx = base4 + k * 64 + lane;
        float4 tv = src4[idx];
        tv.x = __expf(tv.x); tv.y = __expf(tv.y);
        tv.z = __expf(tv.z); tv.w = __expf(tv.w);
        dst4[idx] = tv;
    }
    if (lane < 32) {                              // tail 32 float4 per wave
        const int idx = base4 + 1024 + lane;
        float4 tv = src4[idx];
        tv.x = __expf(tv.x); tv.y = __expf(tv.y);
        tv.z = __expf(tv.z); tv.w = __expf(tv.w);
        dst4[idx] = tv;
    }
    // no barrier: each wave reads only the half it wrote (same-wave LDS dep)

    // ---- gold score (wave 0 only; global reads) ----
    const int* tags = role_label + bv * SS;
    float gold = 0.f;
    if (wid == 0) {
        const int s0 = lane;                      // 0..63
        const int tg0 = tags[s0];
        gold += src[s0 * TT + tg0];
        gold += trans[tg0 * TT + tags[s0 + 1]];
        const int s1 = lane + 64;                 // 64..127
        const int tg1 = tags[s1];
        gold += src[s1 * TT + tg1];
        if (lane < 63) gold += trans[tg1 * TT + tags[s1 + 1]];
        #pragma unroll
        for (int off = 32; off; off >>= 1) gold += __shfl_xor(gold, off);
        gold += startt[tags[0]] + endt[tags[SS - 1]];
    }

    // ---- per-wave weights ----
    // wave0 (forward): W[i]  = exp(trans[i][lane])  ; w64c/w65c = exp(trans[lane][64|65])
    // wave1 (backward): W[j] = exp(trans[lane][j])  ; w64c/w65c = exp(trans[64|65][lane])
    float W[TT], w64c, w65c;
    if (wid == 0) {
        #pragma unroll
        for (int i = 0; i < TT; ++i) W[i] = __expf(trans[i * TT + lane]);
        w64c = __expf(trans[lane * TT + 64]);
        w65c = __expf(trans[lane * TT + 65]);
    } else {
        #pragma unroll
        for (int j = 0; j < TT; ++j) W[j] = __expf(trans[lane * TT + j]);
        w64c = __expf(trans[64 * TT + lane]);
        w65c = __expf(trans[65 * TT + lane]);
    }
    const float c44 = __expf(trans[64 * TT + 64]);
    const float c45 = __expf(trans[64 * TT + 65]);
    const float c54 = __expf(trans[65 * TT + 64]);
    const float c55 = __expf(trans[65 * TT + 65]);

    int esum = 0;
    float F = 0.f, F64 = 0.f, F65 = 0.f;          // wave0 result
    if (wid == 0) {
        // ---- forward: F(0) = exp(start) * X_0; steps t = 1..63 ----
        F   = __expf(startt[lane]) * xl[lane];
        F64 = __expf(startt[64])   * xl[64];
        F65 = __expf(startt[65])   * xl[65];
        float xc   = xl[TT + lane];
        float xc64 = xl[TT + 64];
        float xc65 = xl[TT + 65];
        #pragma unroll 1
        for (int t = 1; t <= 63; ++t) {
            const int tn = (t < 63) ? t + 1 : t;
            const float xn   = xl[tn * TT + lane];
            const float xn64 = xl[tn * TT + 64];
            const float xn65 = xl[tn * TT + 65];

            // cols 64/65: lane-local partials -> DPP reduce (overlaps main stream)
            float p64 = F * w64c;
            float p65 = F * w65c;
            p64 = wave_reduce_sum(p64);
            p65 = wave_reduce_sum(p65);

            float acc0 = F64 * W[64],  acc1 = F65 * W[65];
            float acc2 = 0.f,          acc3 = 0.f;
            #pragma unroll
            for (int i = 0; i < 64; i += 4) {
                acc0 = fmaf(rl(F, i + 0), W[i + 0], acc0);
                acc1 = fmaf(rl(F, i + 1), W[i + 1], acc1);
                acc2 = fmaf(rl(F, i + 2), W[i + 2], acc2);
                acc3 = fmaf(rl(F, i + 3), W[i + 3], acc3);
            }
            const float S   = (acc0 + acc1) + (acc2 + acc3);
            const float S64 = rl(p64, 63) + F64 * c44 + F65 * c54;
            const float S65 = rl(p65, 63) + F64 * c45 + F65 * c55;

            if ((t & 1) == 0) {                    // rescale every 2nd step
                const int sbits = __builtin_amdgcn_readfirstlane(__float_as_int(S));
                const int e = ((sbits >> 23) & 0xff) - 127;
                esum += e;
                const float r = __int_as_float((127 - e) << 23);   // 2^-e exact
                F   = (S   * r) * xc;
                F64 = (S64 * r) * xc64;
                F65 = (S65 * r) * xc65;
            } else {
                F   = S   * xc;
                F64 = S64 * xc64;
                F65 = S65 * xc65;
            }
            xc = xn; xc64 = xn64; xc65 = xn65;
        }
    } else {
        // ---- backward: G(127) = exp(end); steps t = 127..64 ----
        float G   = __expf(endt[lane]);
        float G64 = __expf(endt[64]);
        float G65 = __expf(endt[65]);
        float xc   = xl[127 * TT + lane];
        float xc64 = xl[127 * TT + 64];
        float xc65 = xl[127 * TT + 65];
        #pragma unroll 1
        for (int t = 127; t >= 64; --t) {
            const int tn = (t > 64) ? t - 1 : t;
            const float xn   = xl[tn * TT + lane];
            const float xn64 = xl[tn * TT + 64];
            const float xn65 = xl[tn * TT + 65];

            const float Y   = G * xc;             // Y_j = X_t(j) * G_j
            const float Y64 = G64 * xc64;
            const float Y65 = G65 * xc65;

            // rows 64/65: lane-local partials -> DPP reduce
            float p64 = Y * w64c;
            float p65 = Y * w65c;
            p64 = wave_reduce_sum(p64);
            p65 = wave_reduce_sum(p65);

            float acc0 = Y64 * W[64],  acc1 = Y65 * W[65];
            float acc2 = 0.f,          acc3 = 0.f;
            #pragma unroll
            for (int j = 0; j < 64; j += 4) {
                acc0 = fmaf(rl(Y, j + 0), W[j + 0], acc0);
                acc1 = fmaf(rl(Y, j + 1), W[j + 1], acc1);
                acc2 = fmaf(rl(Y, j + 2), W[j + 2], acc2);
                acc3 = fmaf(rl(Y, j + 3), W[j + 3], acc3);
            }
            const float S   = (acc0 + acc1) + (acc2 + acc3);
            const float S64 = rl(p64, 63) + Y64 * c44 + Y65 * c45;
            const float S65 = rl(p65, 63) + Y64 * c54 + Y65 * c55;

            if ((t & 1) == 0) {                    // rescale every 2nd step
                const int sbits = __builtin_amdgcn_readfirstlane(__float_as_int(S));
                const int e = ((sbits >> 23) & 0xff) - 127;
                esum += e;
                const float r = __int_as_float((127 - e) << 23);
                G   = S   * r;
                G64 = S64 * r;
                G65 = S65 * r;
            } else {
                G   = S;
                G64 = S64;
                G65 = S65;
            }
            xc = xn; xc64 = xn64; xc65 = xn65;
        }
        gbuf[lane] = G;
        if (lane == 0) {
            gbuf[64] = G64;
            gbuf[65] = G65;
            gbuf[66] = __int_as_float(esum);
        }
    }

    __syncthreads();

    if (wid == 0) {
        // ---- stitch: Z = 2^(esumF+esumG) * sum_i F_i * G_i ----
        float prod = F * gbuf[lane];
        #pragma unroll
        for (int off = 32; off; off >>= 1) prod += __shfl_xor(prod, off);
        const float tot = prod + F64 * gbuf[64] + F65 * gbuf[65];
        const int esumG = __float_as_int(gbuf[66]);
        const float log_z = (float)(esum + esumG) * 0.69314718056f + __logf(tot);
        if (lane == 0) ws_nll[bv] = log_z - gold;
    }
}

__global__ __launch_bounds__(64) void crf_reduce_kernel(
    const float* __restrict__ ws_nll, float* __restrict__ out)
{
    const int lane = threadIdx.x;
    float s = ws_nll[lane] + ws_nll[lane + 64] + ws_nll[lane + 128] + ws_nll[lane + 192];
    #pragma unroll
    for (int off = 32; off; off >>= 1) s += __shfl_xor(s, off);
    if (lane == 0) out[0] = s * (1.0f / 256.0f);
}

extern "C" void kernel_launch(void* const* d_in, const int* in_sizes, int n_in,
                              void* d_out, int out_size, void* d_ws, size_t ws_size,
                              hipStream_t stream) {
    const float* score  = (const float*)d_in[0];
    const float* trans  = (const float*)d_in[1];
    const float* startt = (const float*)d_in[2];
    const float* endt   = (const float*)d_in[3];
    const int*   v_label    = (const int*)d_in[4];
    const int*   role_label = (const int*)d_in[5];
    float* out = (float*)d_out;
    float* ws  = (float*)d_ws;

    crf_chain_kernel<<<256, 128, 0, stream>>>(score, trans, startt, endt,
                                              v_label, role_label, ws);
    crf_reduce_kernel<<<1, 64, 0, stream>>>(ws, out);
}